// Round 7
// baseline (126.442 us; speedup 1.0000x reference)
//
#include <hip/hip_runtime.h>

// Fused CNN, conv2 via bf16 MFMA (16x16x32).
// R10: LDS-instruction diet on the R3 skeleton (R3 = 52us best).
//   Cycle model from R3 counters: LDS pipe (per-CU, shared by 4 SIMDs) ~
//   42k cyc img b32 reads + 48k cyc stage-2 b128 B-reads + 34k conflict
//   cycles ~= the whole 125k-cycle runtime -> LDS-pipe-bound.
//   (1) stage-1 img rows via 4x float4 b128: 225 -> 60 LDS instr/thread.
//   (2) stage-2 wave-split 2m x 2n (was 4m x 1n): per wave 2 m-tiles x
//       4 n-tiles -> B-reads 126 -> <=72 b128/wave; A (w2r) doubles to
//       36 global b128/thread on the idle VMEM pipe (L2-hot; R8's mistake
//       was 72 + acc[4][2]=32 + N-split's 4x A traffic).
//   Kept exactly R3-like elsewhere: stride-72 h1t, NO swizzle (R9: XOR in
//   the hot ds_read address path regressed stage-2), fp32 cbuf stride 101,
//   h2t stride 65. R7 lesson: never force min-waves. VGPR target <=64.

typedef __attribute__((ext_vector_type(8))) short short8;   // 8 x bf16 (4 VGPRs)
typedef __attribute__((ext_vector_type(4))) float f32x4;

__device__ inline short f2bf(float f) {   // fp32 -> bf16, round-to-nearest-even
    union { float f; unsigned u; } v; v.f = f;
    unsigned r = (v.u + 0x7FFFu + ((v.u >> 16) & 1u)) >> 16;
    return (short)r;
}

// w2r[s][cout][cin] (bf16), s = ky*3+kx: MFMA A-fragments contiguous in cin.
__global__ __launch_bounds__(256) void prep_w2(const float* __restrict__ w2,
                                               short* __restrict__ w2r) {
    int i = blockIdx.x * 256 + threadIdx.x;      // 9*64*64 = 36864
    if (i >= 36864) return;
    int s = i >> 12, cout = (i >> 6) & 63, cin = i & 63;
    w2r[i] = f2bf(w2[cout * 576 + cin * 9 + s]);
}

// element s (0..15) of a float4[4] register row, s must be a literal
#define EL(arr, s) ((s & 3) == 0 ? arr[(s) >> 2].x : \
                    (s & 3) == 1 ? arr[(s) >> 2].y : \
                    (s & 3) == 2 ? arr[(s) >> 2].z : arr[(s) >> 2].w)

__global__ __launch_bounds__(256) void convnet_fused(
    const float* __restrict__ x,   // [B,1,28,28]
    const float* __restrict__ w1,  // [64,1,3,3]
    const float* __restrict__ b1,  // [64]
    const short* __restrict__ w2r, // [9][64][64] bf16 (prep)
    const float* __restrict__ b2,  // [64]
    const float* __restrict__ w3,  // [10,64,4,4]
    const float* __restrict__ b3,  // [10]
    float* __restrict__ out)       // [B,10]
{
    // Overlay plan (floats):
    //   [0..5184)    h1t bf16 [144 pos][72 cin-stride]  -> later cbuf fp32 [64][101] ([0..6464))
    //   [5184..5968) img 28x28                          -> (absorbed by cbuf)
    //   [6464..7504) h2t fp32 [16 pos][65 stride]
    //   [0..160)     stage-3 partials (cbuf dead by then)
    __shared__ float lds_f[7504];                // 30016 B -> 5 blocks/CU (LDS-wise)
    short* h1t  = (short*)lds_f;
    float* img  = lds_f + 5184;
    float* cbuf = lds_f;                         // conv2buf fp32 [64][101]
    float* h2t  = lds_f + 6464;
    float* prt  = lds_f;

    const int n_img = blockIdx.x;
    const int t = threadIdx.x;
    const int c = t >> 2;        // 0..63
    const int q = t & 3;         // quadrant

    // ---- load input image ----
    const float* img_g = x + (size_t)n_img * 784;
    for (int i = t; i < 784; i += 256) img[i] = img_g[i];
    __syncthreads();

    // ---- stage 1: conv1 + pool 3x3 s2 + relu -> h1t[pos][c] (bf16), no recompute ----
    {
        const int oy = (q >> 1) * 6, ox = (q & 1) * 6;   // pooled quadrant origin
        const int iy0 = 2 * oy, ix0 = 2 * ox;            // input region origin (0 or 12: 16B-aligned)
        float w[9];
        #pragma unroll
        for (int k = 0; k < 9; ++k) w[k] = w1[c * 9 + k];
        const float bias = b1[c];

        float4 in0[4], in1[4], in2[4];                   // ring of 3 input rows, 16 floats each

        #define LOADROW4(dst, row) do { \
            const float4* p4 = (const float4*)(img + (row) * 28 + ix0); \
            dst[0] = p4[0]; dst[1] = p4[1]; dst[2] = p4[2]; dst[3] = p4[3]; } while (0)

        LOADROW4(in0, iy0 + 0);
        LOADROW4(in1, iy0 + 1);
        float cm[3][6];                                  // colmax ring (3 conv rows)

        #pragma unroll
        for (int r = 0; r < 13; ++r) {                   // conv rows, computed once
            LOADROW4(in2, iy0 + r + 2);
            #pragma unroll
            for (int px = 0; px < 6; ++px) cm[r % 3][px] = -1e30f;
            #pragma unroll
            for (int xx = 0; xx < 13; ++xx) {
                float a = bias;
                #pragma unroll
                for (int j = 0; j < 3; ++j) {
                    a += EL(in0, xx + j) * w[j];
                    a += EL(in1, xx + j) * w[3 + j];
                    a += EL(in2, xx + j) * w[6 + j];
                }
                // fold conv value into colmax: px with 2px <= xx <= 2px+2
                if ((xx & 1) == 0) {
                    if (xx >= 2 && xx <= 12) cm[r % 3][xx / 2 - 1] = fmaxf(cm[r % 3][xx / 2 - 1], a);
                    if (xx <= 10)            cm[r % 3][xx / 2]     = fmaxf(cm[r % 3][xx / 2], a);
                } else {
                    cm[r % 3][xx / 2] = fmaxf(cm[r % 3][xx / 2], a);
                }
            }
            if (r >= 2 && (r & 1) == 0) {                // pooled row py = r/2 - 1 complete
                const int py = r / 2 - 1;
                #pragma unroll
                for (int px = 0; px < 6; ++px) {
                    float m = fmaxf(fmaxf(cm[0][px], cm[1][px]), cm[2][px]);
                    h1t[((oy + py) * 12 + ox + px) * 72 + c] = f2bf(fmaxf(m, 0.0f));
                }
            }
            #pragma unroll
            for (int i = 0; i < 4; ++i) { in0[i] = in1[i]; in1[i] = in2[i]; }
        }
        #undef LOADROW4
    }
    __syncthreads();

    // ---- stage 2: conv2 as MFMA GEMM (M=64, N=100 pad 128, K=576), 2m x 2n wave split ----
    // wave wv: mhalf = wv&1 (m-tiles mhalf*2..mhalf*2+1), nhalf = wv>>1 (n-tiles nhalf*4..+3).
    // B-reads <=72 b128/wave (was 126); A from global (L2-hot), 36 b128/thread.
    const int wv = t >> 6, lane = t & 63;
    const int quad = lane >> 4, mrow = lane & 15;
    const int mhalf = wv & 1, nhalf = wv >> 1;
    {
        int pos_b[4];
        #pragma unroll
        for (int nt = 0; nt < 4; ++nt) {
            int n = (nhalf * 4 + nt) * 16 + mrow;
            if (n > 99) n = 99;                           // clamp pad cols (discarded)
            int y = n / 10, xx = n - y * 10;
            pos_b[nt] = (y * 12 + xx) * 72;
        }
        f32x4 acc[2][4];
        #pragma unroll
        for (int mt = 0; mt < 2; ++mt)
            #pragma unroll
            for (int nt = 0; nt < 4; ++nt) acc[mt][nt] = (f32x4){0.f, 0.f, 0.f, 0.f};

        #pragma unroll
        for (int ks = 0; ks < 18; ++ks) {
            const int s = ks >> 1, h = ks & 1;
            const int ky = s / 3, kx = s - ky * 3;
            const int koff = (ky * 12 + kx) * 72 + h * 32 + quad * 8;
            const short8 a0 = *(const short8*)(w2r + s * 4096
                                               + (mhalf * 32 + mrow) * 64 + h * 32 + quad * 8);
            const short8 a1 = *(const short8*)(w2r + s * 4096
                                               + (mhalf * 32 + 16 + mrow) * 64 + h * 32 + quad * 8);
            #pragma unroll
            for (int nt = 0; nt < 4; ++nt) {
                if ((nhalf * 4 + nt) * 16 > 99) continue;   // dead n-tile 7 (wave-uniform)
                const short8 b = *(const short8*)(h1t + pos_b[nt] + koff);
                acc[0][nt] = __builtin_amdgcn_mfma_f32_16x16x32_bf16(a0, b, acc[0][nt], 0, 0, 0);
                acc[1][nt] = __builtin_amdgcn_mfma_f32_16x16x32_bf16(a1, b, acc[1][nt], 0, 0, 0);
            }
        }
        __syncthreads();   // all h1t + img reads done; overlay region reusable
        // epilogue: D[row=quad*4+r (in m-tile)][col=mrow] -> cbuf[cout][n] + bias
        #pragma unroll
        for (int nt = 0; nt < 4; ++nt) {
            const int ntile = nhalf * 4 + nt;
            if (ntile * 16 > 99) continue;                // dead n-tile
            const int n = ntile * 16 + mrow;
            if (n < 100) {
                #pragma unroll
                for (int mt = 0; mt < 2; ++mt) {
                    #pragma unroll
                    for (int r = 0; r < 4; ++r) {
                        const int cout = mhalf * 32 + mt * 16 + quad * 4 + r;
                        cbuf[cout * 101 + n] = acc[mt][nt][r] + b2[cout];
                    }
                }
            }
        }
    }
    __syncthreads();

    // ---- stage 2b: pool 3x3 s2 + relu -> h2t[pos*65+cin] fp32 ----
    {
        const float* cb = cbuf + c * 101;
        #pragma unroll
        for (int k = 0; k < 4; ++k) {
            const int pos = q * 4 + k;
            const int py = pos >> 2, px = pos & 3;
            float m = -1e30f;
            #pragma unroll
            for (int a = 0; a < 3; ++a)
                #pragma unroll
                for (int b = 0; b < 3; ++b)
                    m = fmaxf(m, cb[(2 * py + a) * 10 + (2 * px + b)]);
            h2t[pos * 65 + c] = fmaxf(m, 0.0f);
        }
    }
    __syncthreads();

    // ---- stage 3: conv3 4x4 -> out[n][10] ----
    if (t < 160) {
        const int o = t >> 4, l = t & 15;
        const float* w3o = w3 + o * 1024;
        float s = 0.0f;
        #pragma unroll
        for (int cc = 0; cc < 4; ++cc) {
            const int cin = l * 4 + cc;
            const float4 wv4a = *(const float4*)(w3o + cin * 16);
            const float4 wv4b = *(const float4*)(w3o + cin * 16 + 4);
            const float4 wv4c = *(const float4*)(w3o + cin * 16 + 8);
            const float4 wv4d = *(const float4*)(w3o + cin * 16 + 12);
            const float* hh = h2t + cin;           // h2t[k*65+cin]
            s += hh[0*65] * wv4a.x + hh[1*65] * wv4a.y + hh[2*65] * wv4a.z + hh[3*65] * wv4a.w;
            s += hh[4*65] * wv4b.x + hh[5*65] * wv4b.y + hh[6*65] * wv4b.z + hh[7*65] * wv4b.w;
            s += hh[8*65] * wv4c.x + hh[9*65] * wv4c.y + hh[10*65] * wv4c.z + hh[11*65] * wv4c.w;
            s += hh[12*65] * wv4d.x + hh[13*65] * wv4d.y + hh[14*65] * wv4d.z + hh[15*65] * wv4d.w;
        }
        prt[t] = s;   // cbuf dead (pool reads barriered above)
    }
    __syncthreads();
    if (t < 10) {
        float s = b3[t];
        #pragma unroll
        for (int l = 0; l < 16; ++l) s += prt[t * 16 + l];
        out[(size_t)n_img * 10 + t] = s;
    }
}

extern "C" void kernel_launch(void* const* d_in, const int* in_sizes, int n_in,
                              void* d_out, int out_size, void* d_ws, size_t ws_size,
                              hipStream_t stream) {
    const float* x  = (const float*)d_in[0];
    const float* w1 = (const float*)d_in[1];
    const float* b1 = (const float*)d_in[2];
    const float* w2 = (const float*)d_in[3];
    const float* b2 = (const float*)d_in[4];
    const float* w3 = (const float*)d_in[5];
    const float* b3 = (const float*)d_in[6];
    float* out = (float*)d_out;
    short* w2r = (short*)d_ws;            // 36864 bf16 = 73728 B

    const int B = in_sizes[0] / 784;      // 2048
    prep_w2<<<144, 256, 0, stream>>>(w2, w2r);
    convnet_fused<<<B, 256, 0, stream>>>(x, w1, b1, w2r, b2, w3, b3, out);
}